// Round 2
// baseline (1962.938 us; speedup 1.0000x reference)
//
#include <hip/hip_runtime.h>
#include <math.h>

#define PSZ 256
#define NPATCH 127
#define L 16129            // 127*127
#define KTOP 4
#define TMAIN 256
#define RPT 8              // rows per thread in main kernel
#define ROWS_PER_BLOCK (TMAIN * RPT)   // 2048
#define NROWBLK 8                      // 8*2048 = 16384 >= L
#define ROWPAD 16384

// ---- workspace layout (float elements) ----
static constexpr size_t OFF_CMAX = 0;                         // [2][256][256]
static constexpr size_t OFF_CMIN = OFF_CMAX + 2 * PSZ * PSZ;
static constexpr size_t OFF_REFG = OFF_CMIN + 2 * PSZ * PSZ;
static constexpr size_t OFF_XG   = OFF_REFG + 2 * PSZ * PSZ;
static constexpr size_t OFF_IP   = OFF_XG   + 2 * PSZ * PSZ;  // [2][9][L] input patches
static constexpr size_t OFF_RP   = OFF_IP   + 2 * 9 * L;      // [2][9][L] ref patches
static constexpr size_t OFF_NI   = OFF_RP   + 2 * 9 * L;      // [2][L]
static constexpr size_t OFF_NR   = OFF_NI   + 2 * L;          // [2][L]
static constexpr size_t OFF_MUI  = OFF_NR   + 2 * L;          // [2][9]
static constexpr size_t OFF_MUR  = OFF_MUI  + 18;             // [2][9]
static constexpr size_t OFF_A    = OFF_MUR  + 18;             // [2][L][9]  input_norm (row-major)
static constexpr size_t OFF_B    = OFF_A    + 2 * L * 9;      // [2][9][L]  ref_norm (p-major)
static constexpr size_t OFF_IDX  = OFF_B    + 2 * 9 * L;      // [2][L][4] final idx (int) -- fixed offset
static constexpr size_t OFF_PV   = OFF_IDX  + 2 * L * 4;      // [2][NSEG][ROWPAD][4] partial vals
// OFF_PI(NS) = OFF_PV + 2*NS*ROWPAD*4

template <int NS> struct SegCfg {
  static constexpr int seglen  = (L + NS - 1) / NS;
  static constexpr int mstride = (seglen + 3) & ~3;            // float4-aligned LDS stride
  static constexpr size_t off_pi = OFF_PV + (size_t)2 * NS * ROWPAD * 4;
  static constexpr size_t end_elems = off_pi + (size_t)2 * NS * ROWPAD * 4;
};

__device__ __forceinline__ void ins4(float val, int m,
    float& v0, float& v1, float& v2, float& v3,
    int& i0, int& i1, int& i2, int& i3) {
  // strict > everywhere: equal values keep the earlier (smaller-m) entry,
  // matching jax.lax.top_k tie-break when candidates arrive in ascending m.
  if (val > v3) {
    if (val > v2) {
      v3 = v2; i3 = i2;
      if (val > v1) {
        v2 = v1; i2 = i1;
        if (val > v0) { v1 = v0; i1 = i0; v0 = val; i0 = m; }
        else          { v1 = val; i1 = m; }
      } else { v2 = val; i2 = m; }
    } else { v3 = val; i3 = m; }
  }
}

// k1: per pixel: channel max/min of x, channel mean of ref, copy x -> out[:, :3]
__global__ void k1_pixel(const float* __restrict__ x, const float* __restrict__ ref,
                         float* __restrict__ ws, float* __restrict__ out) {
  int id = blockIdx.x * 256 + threadIdx.x;
  if (id >= 2 * PSZ * PSZ) return;
  int b = id >> 16;
  int pix = id & 0xFFFF;
  const float* xb = x + (size_t)b * 3 * PSZ * PSZ + pix;
  float c0 = xb[0], c1 = xb[PSZ * PSZ], c2 = xb[2 * PSZ * PSZ];
  ws[OFF_CMAX + id] = fmaxf(fmaxf(c0, c1), c2);
  ws[OFF_CMIN + id] = fminf(fminf(c0, c1), c2);
  const float* rb = ref + (size_t)b * 3 * PSZ * PSZ + pix;
  ws[OFF_REFG + id] = (rb[0] + rb[PSZ * PSZ] + rb[2 * PSZ * PSZ]) / 3.0f;
  float* ob = out + (size_t)b * 7 * PSZ * PSZ + pix;
  ob[0] = c0; ob[PSZ * PSZ] = c1; ob[2 * PSZ * PSZ] = c2;
}

// k2: x_gray = 3x3 clipped-window max of cmax - cmin
__global__ void k2_gray(float* __restrict__ ws) {
  int id = blockIdx.x * 256 + threadIdx.x;
  if (id >= 2 * PSZ * PSZ) return;
  int b = id >> 16;
  int pix = id & 0xFFFF;
  int y = pix >> 8, xx = pix & 255;
  const float* cm = ws + OFF_CMAX + ((size_t)b << 16);
  float m = -3.402823466e+38f;
  for (int dy = -1; dy <= 1; ++dy) {
    int yy = y + dy;
    if (yy < 0 || yy > 255) continue;
    for (int dx = -1; dx <= 1; ++dx) {
      int xc = xx + dx;
      if (xc < 0 || xc > 255) continue;
      m = fmaxf(m, cm[yy * PSZ + xc]);
    }
  }
  ws[OFF_XG + id] = m - ws[OFF_CMIN + id];
}

// k3: unfold patches (p = 3*di + dj), plus per-patch norms (uncentered, f32 like reference)
__global__ void k3_patch(float* __restrict__ ws) {
  int id = blockIdx.x * 256 + threadIdx.x;
  if (id >= 2 * L) return;
  int b = id / L, m = id % L;
  int i = m / NPATCH, j = m % NPATCH;
  const float* xg = ws + OFF_XG + ((size_t)b << 16);
  const float* rg = ws + OFF_REFG + ((size_t)b << 16);
  float si = 0.f, sr = 0.f;
  for (int di = 0; di < 3; ++di) {
    for (int dj = 0; dj < 3; ++dj) {
      int p = di * 3 + dj;
      float vi = xg[(2 * i + di) * PSZ + 2 * j + dj];
      float vr = rg[(2 * i + di) * PSZ + 2 * j + dj];
      ws[OFF_IP + ((size_t)b * 9 + p) * L + m] = vi;
      ws[OFF_RP + ((size_t)b * 9 + p) * L + m] = vr;
      si += vi * vi;
      sr += vr * vr;
    }
  }
  ws[OFF_NI + id] = sqrtf(si);
  ws[OFF_NR + id] = sqrtf(sr);
}

// k4: per-(b,p) mean over L in f64 (deterministic tree reduction)
__global__ void k4_mean(float* __restrict__ ws) {
  __shared__ double sm[256];
  int which = blockIdx.x / 18;  // 0 = ip, 1 = rp
  int bp = blockIdx.x % 18;
  const float* src = ws + (which ? OFF_RP : OFF_IP) + (size_t)bp * L;
  double s = 0.0;
  for (int l = threadIdx.x; l < L; l += 256) s += (double)src[l];
  sm[threadIdx.x] = s;
  __syncthreads();
  for (int st = 128; st > 0; st >>= 1) {
    if ((int)threadIdx.x < st) sm[threadIdx.x] += sm[threadIdx.x + st];
    __syncthreads();
  }
  if (threadIdx.x == 0)
    ws[(which ? OFF_MUR : OFF_MUI) + bp] = (float)(sm[0] / (double)L);
}

// k5: build normalized matrices. A[b][l][9] = (ip - muI)/nI ; B[b][9][L] = (rp - muR)/nR
__global__ void k5_norm(float* __restrict__ ws) {
  int id = blockIdx.x * 256 + threadIdx.x;
  if (id >= 2 * L) return;
  int b = id / L, l = id % L;
  float ni = ws[OFF_NI + id], nr = ws[OFF_NR + id];
  for (int p = 0; p < 9; ++p) {
    float mi = ws[OFF_MUI + b * 9 + p];
    float mr = ws[OFF_MUR + b * 9 + p];
    float vi = ws[OFF_IP + ((size_t)b * 9 + p) * L + l];
    float vr = ws[OFF_RP + ((size_t)b * 9 + p) * L + l];
    ws[OFF_A + ((size_t)b * L + l) * 9 + p] = (vi - mi) / ni;
    ws[OFF_B + ((size_t)b * 9 + p) * L + l] = (vr - mr) / nr;
  }
}

// k6: fused ncc + per-segment top-4.
// grid: 2(b) x NROWBLK(8) x NS, 256 threads, 8 rows/thread, 4 m/iter.
// amdgpu_waves_per_eu(2,2): cap VGPR at 256 (demand ~220) -> no scratch spill,
// 2 waves/SIMD. (Round 1: __launch_bounds__(256,2) produced a 64-VGPR cap and
// a 163 MB scratch-spill round trip -> 1808 us at 10% VALUBusy.)
template <int NS>
__attribute__((amdgpu_waves_per_eu(2, 2)))
__global__ void __launch_bounds__(TMAIN) k6_topk(float* __restrict__ ws) {
  constexpr int SEGLEN  = SegCfg<NS>::seglen;
  constexpr int MSTRIDE = SegCfg<NS>::mstride;
  constexpr size_t OFF_PI = SegCfg<NS>::off_pi;
  __shared__ float lds[9 * MSTRIDE];

  int bid = blockIdx.x;
  int seg = bid % NS;
  int rowblk = (bid / NS) % NROWBLK;
  int b = bid / (NS * NROWBLK);
  int m0 = seg * SEGLEN;
  int mend = m0 + SEGLEN;
  if (mend > L) mend = L;
  int mlen = mend - m0;

  const float* Bg = ws + OFF_B + (size_t)b * 9 * L + m0;
  for (int p = 0; p < 9; ++p)
    for (int mm = threadIdx.x; mm < mlen; mm += TMAIN)
      lds[p * MSTRIDE + mm] = Bg[(size_t)p * L + mm];
  __syncthreads();

  int row0 = rowblk * ROWS_PER_BLOCK + threadIdx.x * RPT;
  float a[RPT][9];
#pragma unroll
  for (int r = 0; r < RPT; ++r) {
    int row = row0 + r;
    if (row > L - 1) row = L - 1;
    const float* Ap = ws + OFF_A + ((size_t)b * L + row) * 9;
#pragma unroll
    for (int p = 0; p < 9; ++p) a[r][p] = Ap[p];
  }

  float tv[RPT][4];
  int ti[RPT][4];
#pragma unroll
  for (int r = 0; r < RPT; ++r) {
#pragma unroll
    for (int q = 0; q < 4; ++q) { tv[r][q] = -3.402823466e+38f; ti[r][q] = 0; }
  }

  int mlen4 = mlen & ~3;
  for (int mm = 0; mm < mlen4; mm += 4) {
    float s[RPT][4];
    {
      const float4 bq = *reinterpret_cast<const float4*>(&lds[mm]);
#pragma unroll
      for (int r = 0; r < RPT; ++r) {
        s[r][0] = a[r][0] * bq.x;
        s[r][1] = a[r][0] * bq.y;
        s[r][2] = a[r][0] * bq.z;
        s[r][3] = a[r][0] * bq.w;
      }
    }
#pragma unroll
    for (int p = 1; p < 9; ++p) {
      const float4 bq = *reinterpret_cast<const float4*>(&lds[p * MSTRIDE + mm]);
#pragma unroll
      for (int r = 0; r < RPT; ++r) {
        s[r][0] = fmaf(a[r][p], bq.x, s[r][0]);
        s[r][1] = fmaf(a[r][p], bq.y, s[r][1]);
        s[r][2] = fmaf(a[r][p], bq.z, s[r][2]);
        s[r][3] = fmaf(a[r][p], bq.w, s[r][3]);
      }
    }
#pragma unroll
    for (int r = 0; r < RPT; ++r) {
      float rm = fmaxf(fmaxf(s[r][0], s[r][1]), fmaxf(s[r][2], s[r][3]));
      if (rm > tv[r][3]) {
        ins4(s[r][0], m0 + mm + 0, tv[r][0], tv[r][1], tv[r][2], tv[r][3], ti[r][0], ti[r][1], ti[r][2], ti[r][3]);
        ins4(s[r][1], m0 + mm + 1, tv[r][0], tv[r][1], tv[r][2], tv[r][3], ti[r][0], ti[r][1], ti[r][2], ti[r][3]);
        ins4(s[r][2], m0 + mm + 2, tv[r][0], tv[r][1], tv[r][2], tv[r][3], ti[r][0], ti[r][1], ti[r][2], ti[r][3]);
        ins4(s[r][3], m0 + mm + 3, tv[r][0], tv[r][1], tv[r][2], tv[r][3], ti[r][0], ti[r][1], ti[r][2], ti[r][3]);
      }
    }
  }
  // tail (ascending m preserves tie semantics)
  for (int mm = mlen4; mm < mlen; ++mm) {
    float bb[9];
#pragma unroll
    for (int p = 0; p < 9; ++p) bb[p] = lds[p * MSTRIDE + mm];
#pragma unroll
    for (int r = 0; r < RPT; ++r) {
      float sv = a[r][0] * bb[0];
#pragma unroll
      for (int p = 1; p < 9; ++p) sv = fmaf(a[r][p], bb[p], sv);
      if (sv > tv[r][3])
        ins4(sv, m0 + mm, tv[r][0], tv[r][1], tv[r][2], tv[r][3], ti[r][0], ti[r][1], ti[r][2], ti[r][3]);
    }
  }

  int* wsi = (int*)ws;
#pragma unroll
  for (int r = 0; r < RPT; ++r) {
    int row = row0 + r;
    if (row < L) {
      size_t base = (((size_t)b * NS + seg) * ROWPAD + row) * 4;
#pragma unroll
      for (int q = 0; q < 4; ++q) {
        ws[OFF_PV + base + q] = tv[r][q];
        wsi[OFF_PI + base + q] = ti[r][q];
      }
    }
  }
}

// k7: merge per-segment top-4 (segments ascending -> tie-break = lower m first)
template <int NS>
__global__ void k7_merge(float* __restrict__ ws) {
  constexpr size_t OFF_PI = SegCfg<NS>::off_pi;
  int id = blockIdx.x * 256 + threadIdx.x;
  if (id >= 2 * L) return;
  int b = id / L, row = id % L;
  float v0 = -3.402823466e+38f, v1 = v0, v2 = v0, v3 = v0;
  int i0 = 0, i1 = 0, i2 = 0, i3 = 0;
  const int* wsi_c = (const int*)ws;
  for (int s = 0; s < NS; ++s) {
    size_t base = (((size_t)b * NS + s) * ROWPAD + row) * 4;
    for (int q = 0; q < 4; ++q) {
      float val = ws[OFF_PV + base + q];
      int m = wsi_c[OFF_PI + base + q];
      ins4(val, m, v0, v1, v2, v3, i0, i1, i2, i3);
    }
  }
  int* wsi = (int*)ws;
  size_t ib = OFF_IDX + (size_t)id * 4;
  wsi[ib] = i0; wsi[ib + 1] = i1; wsi[ib + 2] = i2; wsi[ib + 3] = i3;
}

// k8: fold (overlap-add) via per-output-pixel gather; di/dj ascending matches reference add order
__global__ void k8_fold(const float* __restrict__ ws, float* __restrict__ out) {
  int id = blockIdx.x * 256 + threadIdx.x;
  if (id >= 2 * KTOP * PSZ * PSZ) return;
  int b = id / (KTOP * PSZ * PSZ);
  int rem = id % (KTOP * PSZ * PSZ);
  int kk = rem >> 16;
  int pix = rem & 0xFFFF;
  int y = pix >> 8, xx = pix & 255;
  const int* wsi = (const int*)ws;
  float acc = 0.f;
  for (int di = 0; di < 3; ++di) {
    int yy = y - di;
    if (yy < 0 || (yy & 1) || (yy >> 1) >= NPATCH) continue;
    int i = yy >> 1;
    for (int dj = 0; dj < 3; ++dj) {
      int xc = xx - dj;
      if (xc < 0 || (xc & 1) || (xc >> 1) >= NPATCH) continue;
      int j = xc >> 1;
      int l = i * NPATCH + j;
      int m = wsi[OFF_IDX + ((size_t)b * L + l) * 4 + kk];
      acc += ws[OFF_RP + ((size_t)b * 9 + di * 3 + dj) * L + m];
    }
  }
  out[(((size_t)b * 7 + 3 + kk) * PSZ + y) * PSZ + xx] = acc;
}

extern "C" void kernel_launch(void* const* d_in, const int* in_sizes, int n_in,
                              void* d_out, int out_size, void* d_ws, size_t ws_size,
                              hipStream_t stream) {
  const float* x = (const float*)d_in[0];
  const float* ref = (const float*)d_in[1];
  float* ws = (float*)d_ws;
  float* out = (float*)d_out;

  k1_pixel<<<512, 256, 0, stream>>>(x, ref, ws, out);
  k2_gray<<<512, 256, 0, stream>>>(ws);
  k3_patch<<<(2 * L + 255) / 256, 256, 0, stream>>>(ws);
  k4_mean<<<36, 256, 0, stream>>>(ws);
  k5_norm<<<(2 * L + 255) / 256, 256, 0, stream>>>(ws);

  // NSEG=32 gives 512 blocks (2 blocks/CU) but needs ~41 MB of ws; fall back
  // to NSEG=16 (~24 MB, known-good) if the workspace is smaller. ws_size is
  // fixed for the session -> deterministic.
  bool big = ws_size >= SegCfg<32>::end_elems * sizeof(float);
  if (big) {
    k6_topk<32><<<2 * NROWBLK * 32, TMAIN, 0, stream>>>(ws);
    k7_merge<32><<<(2 * L + 255) / 256, 256, 0, stream>>>(ws);
  } else {
    k6_topk<16><<<2 * NROWBLK * 16, TMAIN, 0, stream>>>(ws);
    k7_merge<16><<<(2 * L + 255) / 256, 256, 0, stream>>>(ws);
  }
  k8_fold<<<(2 * KTOP * PSZ * PSZ + 255) / 256, 256, 0, stream>>>(ws, out);
}

// Round 3
// 1286.673 us; speedup vs baseline: 1.5256x; 1.5256x over previous
//
#include <hip/hip_runtime.h>
#include <math.h>

#define PSZ 256
#define NPATCH 127
#define L 16129            // 127*127
#define KTOP 4
#define TMAIN 256
#define RPT 4              // rows per thread in main kernel (4 -> ~100 VGPR state, no spill)
#define ROWS_PER_BLOCK (TMAIN * RPT)   // 1024
#define NROWBLK 16                     // 16*1024 = 16384 >= L
#define ROWPAD 16384

// ---- workspace layout (float elements) ----
static constexpr size_t OFF_CMAX = 0;                         // [2][256][256]
static constexpr size_t OFF_CMIN = OFF_CMAX + 2 * PSZ * PSZ;
static constexpr size_t OFF_REFG = OFF_CMIN + 2 * PSZ * PSZ;
static constexpr size_t OFF_XG   = OFF_REFG + 2 * PSZ * PSZ;
static constexpr size_t OFF_IP   = OFF_XG   + 2 * PSZ * PSZ;  // [2][9][L] input patches
static constexpr size_t OFF_RP   = OFF_IP   + 2 * 9 * L;      // [2][9][L] ref patches
static constexpr size_t OFF_NI   = OFF_RP   + 2 * 9 * L;      // [2][L]
static constexpr size_t OFF_NR   = OFF_NI   + 2 * L;          // [2][L]
static constexpr size_t OFF_MUI  = OFF_NR   + 2 * L;          // [2][9]
static constexpr size_t OFF_MUR  = OFF_MUI  + 18;             // [2][9]
static constexpr size_t OFF_A    = OFF_MUR  + 18;             // [2][L][9]  input_norm (row-major)
static constexpr size_t OFF_B    = OFF_A    + 2 * L * 9;      // [2][9][L]  ref_norm (p-major)
static constexpr size_t OFF_IDX  = OFF_B    + 2 * 9 * L;      // [2][L][4] final idx (int)
static constexpr size_t OFF_PV   = OFF_IDX  + 2 * L * 4;      // [2][NS][ROWPAD][4] partial vals
// OFF_PI(NS) = OFF_PV + 2*NS*ROWPAD*4

template <int NS> struct SegCfg {
  static constexpr int seglen  = (L + NS - 1) / NS;
  static constexpr int mstride = (seglen + 3) & ~3;            // float4-aligned LDS stride
  static constexpr size_t off_pi = OFF_PV + (size_t)2 * NS * ROWPAD * 4;
  static constexpr size_t end_elems = off_pi + (size_t)2 * NS * ROWPAD * 4;
};

__device__ __forceinline__ void ins4(float val, int m,
    float& v0, float& v1, float& v2, float& v3,
    int& i0, int& i1, int& i2, int& i3) {
  // strict > everywhere: equal values keep the earlier (smaller-m) entry,
  // matching jax.lax.top_k tie-break when candidates arrive in ascending m.
  if (val > v3) {
    if (val > v2) {
      v3 = v2; i3 = i2;
      if (val > v1) {
        v2 = v1; i2 = i1;
        if (val > v0) { v1 = v0; i1 = i0; v0 = val; i0 = m; }
        else          { v1 = val; i1 = m; }
      } else { v2 = val; i2 = m; }
    } else { v3 = val; i3 = m; }
  }
}

// k1: per pixel: channel max/min of x, channel mean of ref, copy x -> out[:, :3]
__global__ void k1_pixel(const float* __restrict__ x, const float* __restrict__ ref,
                         float* __restrict__ ws, float* __restrict__ out) {
  int id = blockIdx.x * 256 + threadIdx.x;
  if (id >= 2 * PSZ * PSZ) return;
  int b = id >> 16;
  int pix = id & 0xFFFF;
  const float* xb = x + (size_t)b * 3 * PSZ * PSZ + pix;
  float c0 = xb[0], c1 = xb[PSZ * PSZ], c2 = xb[2 * PSZ * PSZ];
  ws[OFF_CMAX + id] = fmaxf(fmaxf(c0, c1), c2);
  ws[OFF_CMIN + id] = fminf(fminf(c0, c1), c2);
  const float* rb = ref + (size_t)b * 3 * PSZ * PSZ + pix;
  ws[OFF_REFG + id] = (rb[0] + rb[PSZ * PSZ] + rb[2 * PSZ * PSZ]) / 3.0f;
  float* ob = out + (size_t)b * 7 * PSZ * PSZ + pix;
  ob[0] = c0; ob[PSZ * PSZ] = c1; ob[2 * PSZ * PSZ] = c2;
}

// k2: x_gray = 3x3 clipped-window max of cmax - cmin
__global__ void k2_gray(float* __restrict__ ws) {
  int id = blockIdx.x * 256 + threadIdx.x;
  if (id >= 2 * PSZ * PSZ) return;
  int b = id >> 16;
  int pix = id & 0xFFFF;
  int y = pix >> 8, xx = pix & 255;
  const float* cm = ws + OFF_CMAX + ((size_t)b << 16);
  float m = -3.402823466e+38f;
  for (int dy = -1; dy <= 1; ++dy) {
    int yy = y + dy;
    if (yy < 0 || yy > 255) continue;
    for (int dx = -1; dx <= 1; ++dx) {
      int xc = xx + dx;
      if (xc < 0 || xc > 255) continue;
      m = fmaxf(m, cm[yy * PSZ + xc]);
    }
  }
  ws[OFF_XG + id] = m - ws[OFF_CMIN + id];
}

// k3: unfold patches (p = 3*di + dj), plus per-patch norms (uncentered, f32 like reference)
__global__ void k3_patch(float* __restrict__ ws) {
  int id = blockIdx.x * 256 + threadIdx.x;
  if (id >= 2 * L) return;
  int b = id / L, m = id % L;
  int i = m / NPATCH, j = m % NPATCH;
  const float* xg = ws + OFF_XG + ((size_t)b << 16);
  const float* rg = ws + OFF_REFG + ((size_t)b << 16);
  float si = 0.f, sr = 0.f;
  for (int di = 0; di < 3; ++di) {
    for (int dj = 0; dj < 3; ++dj) {
      int p = di * 3 + dj;
      float vi = xg[(2 * i + di) * PSZ + 2 * j + dj];
      float vr = rg[(2 * i + di) * PSZ + 2 * j + dj];
      ws[OFF_IP + ((size_t)b * 9 + p) * L + m] = vi;
      ws[OFF_RP + ((size_t)b * 9 + p) * L + m] = vr;
      si += vi * vi;
      sr += vr * vr;
    }
  }
  ws[OFF_NI + id] = sqrtf(si);
  ws[OFF_NR + id] = sqrtf(sr);
}

// k4: per-(b,p) mean over L in f64 (deterministic tree reduction)
__global__ void k4_mean(float* __restrict__ ws) {
  __shared__ double sm[256];
  int which = blockIdx.x / 18;  // 0 = ip, 1 = rp
  int bp = blockIdx.x % 18;
  const float* src = ws + (which ? OFF_RP : OFF_IP) + (size_t)bp * L;
  double s = 0.0;
  for (int l = threadIdx.x; l < L; l += 256) s += (double)src[l];
  sm[threadIdx.x] = s;
  __syncthreads();
  for (int st = 128; st > 0; st >>= 1) {
    if ((int)threadIdx.x < st) sm[threadIdx.x] += sm[threadIdx.x + st];
    __syncthreads();
  }
  if (threadIdx.x == 0)
    ws[(which ? OFF_MUR : OFF_MUI) + bp] = (float)(sm[0] / (double)L);
}

// k5: build normalized matrices. A[b][l][9] = (ip - muI)/nI ; B[b][9][L] = (rp - muR)/nR
__global__ void k5_norm(float* __restrict__ ws) {
  int id = blockIdx.x * 256 + threadIdx.x;
  if (id >= 2 * L) return;
  int b = id / L, l = id % L;
  float ni = ws[OFF_NI + id], nr = ws[OFF_NR + id];
  for (int p = 0; p < 9; ++p) {
    float mi = ws[OFF_MUI + b * 9 + p];
    float mr = ws[OFF_MUR + b * 9 + p];
    float vi = ws[OFF_IP + ((size_t)b * 9 + p) * L + l];
    float vr = ws[OFF_RP + ((size_t)b * 9 + p) * L + l];
    ws[OFF_A + ((size_t)b * L + l) * 9 + p] = (vi - mi) / ni;
    ws[OFF_B + ((size_t)b * 9 + p) * L + l] = (vr - mr) / nr;
  }
}

// k6: fused ncc + per-segment top-4.
// grid: 2(b) x NROWBLK(16) x NS(32) = 1024 blocks (4/CU), 256 threads,
// 4 rows/thread, 4 m/iter. State ~100 VGPR -> fits a 128-VGPR (4 waves/EU)
// budget with no spill. waves_per_eu(2,4) keeps the allocator from
// squeezing to 64-88 VGPR and spilling (rounds 1-2: 0.18-2.1 GB scratch
// traffic, VALUBusy 11%).
template <int NS>
__global__ void __attribute__((amdgpu_waves_per_eu(2, 4)))
__launch_bounds__(TMAIN) k6_topk(float* __restrict__ ws) {
  constexpr int SEGLEN  = SegCfg<NS>::seglen;
  constexpr int MSTRIDE = SegCfg<NS>::mstride;
  constexpr size_t OFF_PI = SegCfg<NS>::off_pi;
  __shared__ float lds[9 * MSTRIDE];

  int bid = blockIdx.x;
  int seg = bid % NS;
  int rowblk = (bid / NS) % NROWBLK;
  int b = bid / (NS * NROWBLK);
  int m0 = seg * SEGLEN;
  int mend = m0 + SEGLEN;
  if (mend > L) mend = L;
  int mlen = mend - m0;

  const float* Bg = ws + OFF_B + (size_t)b * 9 * L + m0;
  for (int p = 0; p < 9; ++p)
    for (int mm = threadIdx.x; mm < mlen; mm += TMAIN)
      lds[p * MSTRIDE + mm] = Bg[(size_t)p * L + mm];
  __syncthreads();

  int row0 = rowblk * ROWS_PER_BLOCK + threadIdx.x * RPT;
  float a[RPT][9];
#pragma unroll
  for (int r = 0; r < RPT; ++r) {
    int row = row0 + r;
    if (row > L - 1) row = L - 1;
    const float* Ap = ws + OFF_A + ((size_t)b * L + row) * 9;
#pragma unroll
    for (int p = 0; p < 9; ++p) a[r][p] = Ap[p];
  }

  float tv[RPT][4];
  int ti[RPT][4];
#pragma unroll
  for (int r = 0; r < RPT; ++r) {
#pragma unroll
    for (int q = 0; q < 4; ++q) { tv[r][q] = -3.402823466e+38f; ti[r][q] = 0; }
  }

  int mlen4 = mlen & ~3;
  for (int mm = 0; mm < mlen4; mm += 4) {
    float s[RPT][4];
    {
      const float4 bq = *reinterpret_cast<const float4*>(&lds[mm]);
#pragma unroll
      for (int r = 0; r < RPT; ++r) {
        s[r][0] = a[r][0] * bq.x;
        s[r][1] = a[r][0] * bq.y;
        s[r][2] = a[r][0] * bq.z;
        s[r][3] = a[r][0] * bq.w;
      }
    }
#pragma unroll
    for (int p = 1; p < 9; ++p) {
      const float4 bq = *reinterpret_cast<const float4*>(&lds[p * MSTRIDE + mm]);
#pragma unroll
      for (int r = 0; r < RPT; ++r) {
        s[r][0] = fmaf(a[r][p], bq.x, s[r][0]);
        s[r][1] = fmaf(a[r][p], bq.y, s[r][1]);
        s[r][2] = fmaf(a[r][p], bq.z, s[r][2]);
        s[r][3] = fmaf(a[r][p], bq.w, s[r][3]);
      }
    }
#pragma unroll
    for (int r = 0; r < RPT; ++r) {
      float rm = fmaxf(fmaxf(s[r][0], s[r][1]), fmaxf(s[r][2], s[r][3]));
      if (rm > tv[r][3]) {
        ins4(s[r][0], m0 + mm + 0, tv[r][0], tv[r][1], tv[r][2], tv[r][3], ti[r][0], ti[r][1], ti[r][2], ti[r][3]);
        ins4(s[r][1], m0 + mm + 1, tv[r][0], tv[r][1], tv[r][2], tv[r][3], ti[r][0], ti[r][1], ti[r][2], ti[r][3]);
        ins4(s[r][2], m0 + mm + 2, tv[r][0], tv[r][1], tv[r][2], tv[r][3], ti[r][0], ti[r][1], ti[r][2], ti[r][3]);
        ins4(s[r][3], m0 + mm + 3, tv[r][0], tv[r][1], tv[r][2], tv[r][3], ti[r][0], ti[r][1], ti[r][2], ti[r][3]);
      }
    }
  }
  // tail (ascending m preserves tie semantics)
  for (int mm = mlen4; mm < mlen; ++mm) {
    float bb[9];
#pragma unroll
    for (int p = 0; p < 9; ++p) bb[p] = lds[p * MSTRIDE + mm];
#pragma unroll
    for (int r = 0; r < RPT; ++r) {
      float sv = a[r][0] * bb[0];
#pragma unroll
      for (int p = 1; p < 9; ++p) sv = fmaf(a[r][p], bb[p], sv);
      if (sv > tv[r][3])
        ins4(sv, m0 + mm, tv[r][0], tv[r][1], tv[r][2], tv[r][3], ti[r][0], ti[r][1], ti[r][2], ti[r][3]);
    }
  }

  int* wsi = (int*)ws;
#pragma unroll
  for (int r = 0; r < RPT; ++r) {
    int row = row0 + r;
    if (row < L) {
      size_t base = (((size_t)b * NS + seg) * ROWPAD + row) * 4;
#pragma unroll
      for (int q = 0; q < 4; ++q) {
        ws[OFF_PV + base + q] = tv[r][q];
        wsi[OFF_PI + base + q] = ti[r][q];
      }
    }
  }
}

// k7: merge per-segment top-4 (segments ascending -> tie-break = lower m first)
template <int NS>
__global__ void k7_merge(float* __restrict__ ws) {
  constexpr size_t OFF_PI = SegCfg<NS>::off_pi;
  int id = blockIdx.x * 256 + threadIdx.x;
  if (id >= 2 * L) return;
  int b = id / L, row = id % L;
  float v0 = -3.402823466e+38f, v1 = v0, v2 = v0, v3 = v0;
  int i0 = 0, i1 = 0, i2 = 0, i3 = 0;
  const int* wsi_c = (const int*)ws;
  for (int s = 0; s < NS; ++s) {
    size_t base = (((size_t)b * NS + s) * ROWPAD + row) * 4;
    for (int q = 0; q < 4; ++q) {
      float val = ws[OFF_PV + base + q];
      int m = wsi_c[OFF_PI + base + q];
      ins4(val, m, v0, v1, v2, v3, i0, i1, i2, i3);
    }
  }
  int* wsi = (int*)ws;
  size_t ib = OFF_IDX + (size_t)id * 4;
  wsi[ib] = i0; wsi[ib + 1] = i1; wsi[ib + 2] = i2; wsi[ib + 3] = i3;
}

// k8: fold (overlap-add) via per-output-pixel gather; di/dj ascending matches reference add order
__global__ void k8_fold(const float* __restrict__ ws, float* __restrict__ out) {
  int id = blockIdx.x * 256 + threadIdx.x;
  if (id >= 2 * KTOP * PSZ * PSZ) return;
  int b = id / (KTOP * PSZ * PSZ);
  int rem = id % (KTOP * PSZ * PSZ);
  int kk = rem >> 16;
  int pix = rem & 0xFFFF;
  int y = pix >> 8, xx = pix & 255;
  const int* wsi = (const int*)ws;
  float acc = 0.f;
  for (int di = 0; di < 3; ++di) {
    int yy = y - di;
    if (yy < 0 || (yy & 1) || (yy >> 1) >= NPATCH) continue;
    int i = yy >> 1;
    for (int dj = 0; dj < 3; ++dj) {
      int xc = xx - dj;
      if (xc < 0 || (xc & 1) || (xc >> 1) >= NPATCH) continue;
      int j = xc >> 1;
      int l = i * NPATCH + j;
      int m = wsi[OFF_IDX + ((size_t)b * L + l) * 4 + kk];
      acc += ws[OFF_RP + ((size_t)b * 9 + di * 3 + dj) * L + m];
    }
  }
  out[(((size_t)b * 7 + 3 + kk) * PSZ + y) * PSZ + xx] = acc;
}

extern "C" void kernel_launch(void* const* d_in, const int* in_sizes, int n_in,
                              void* d_out, int out_size, void* d_ws, size_t ws_size,
                              hipStream_t stream) {
  const float* x = (const float*)d_in[0];
  const float* ref = (const float*)d_in[1];
  float* ws = (float*)d_ws;
  float* out = (float*)d_out;

  k1_pixel<<<512, 256, 0, stream>>>(x, ref, ws, out);
  k2_gray<<<512, 256, 0, stream>>>(ws);
  k3_patch<<<(2 * L + 255) / 256, 256, 0, stream>>>(ws);
  k4_mean<<<36, 256, 0, stream>>>(ws);
  k5_norm<<<(2 * L + 255) / 256, 256, 0, stream>>>(ws);

  // NS=32 gives 1024 blocks (4 blocks/CU); needs ~39 MB of ws (proven present
  // in round 2 -- this path ran). Fallback NS=16 (~22 MB) otherwise.
  // ws_size is fixed for the session -> deterministic.
  bool big = ws_size >= SegCfg<32>::end_elems * sizeof(float);
  if (big) {
    k6_topk<32><<<2 * NROWBLK * 32, TMAIN, 0, stream>>>(ws);
    k7_merge<32><<<(2 * L + 255) / 256, 256, 0, stream>>>(ws);
  } else {
    k6_topk<16><<<2 * NROWBLK * 16, TMAIN, 0, stream>>>(ws);
    k7_merge<16><<<(2 * L + 255) / 256, 256, 0, stream>>>(ws);
  }
  k8_fold<<<(2 * KTOP * PSZ * PSZ + 255) / 256, 256, 0, stream>>>(ws, out);
}

// Round 4
// 391.469 us; speedup vs baseline: 5.0143x; 3.2868x over previous
//
#include <hip/hip_runtime.h>
#include <math.h>

#define PSZ 256
#define NPATCH 127
#define L 16129            // 127*127
#define KTOP 4
#define TMAIN 256
#define RPT 2              // rows per thread: state ~55 VGPR -> fits the 64-VGPR cap
#define ROWS_PER_BLOCK (TMAIN * RPT)   // 512
#define NROWBLK 32                     // 32*512 = 16384 >= L
#define NS 16
#define SEGLEN 1009                    // ceil(L/16)
#define MSTRIDE 1012                   // float4-aligned LDS stride
#define ROWPAD 16384

// ---- workspace layout (float elements, all 16B-aligned) ----
static constexpr size_t OFF_CMAX = 0;                          // [2][256][256]
static constexpr size_t OFF_CMIN = OFF_CMAX + 2 * PSZ * PSZ;
static constexpr size_t OFF_REFG = OFF_CMIN + 2 * PSZ * PSZ;
static constexpr size_t OFF_XG   = OFF_REFG + 2 * PSZ * PSZ;
static constexpr size_t OFF_NI   = OFF_XG   + 2 * PSZ * PSZ;   // [2L]
static constexpr size_t OFF_NR   = OFF_NI   + 32260;
static constexpr size_t OFF_MUI  = OFF_NR   + 32260;           // [18]
static constexpr size_t OFF_MUR  = OFF_MUI  + 20;
static constexpr size_t OFF_A    = OFF_MUR  + 20;              // [2][L][9] input_norm
static constexpr size_t OFF_B    = OFF_A    + 290324;          // [2][9][L] ref_norm
static constexpr size_t OFF_IDX  = OFF_B    + 290324;          // [2][L][4] int
static constexpr size_t OFF_PV   = OFF_IDX  + 2 * L * 4;       // [2][NS][ROWPAD][4]
static constexpr size_t OFF_PI   = OFF_PV   + (size_t)2 * NS * ROWPAD * 4;
// end ~= 5.5M floats (22 MB) << proven ws >= 74 MB (rounds 2-3 ran the NS=32 path)

__device__ __forceinline__ void ins4(float val, int m,
    float& v0, float& v1, float& v2, float& v3,
    int& i0, int& i1, int& i2, int& i3) {
  if (val > v3) {
    if (val > v2) {
      v3 = v2; i3 = i2;
      if (val > v1) {
        v2 = v1; i2 = i1;
        if (val > v0) { v1 = v0; i1 = i0; v0 = val; i0 = m; }
        else          { v1 = val; i1 = m; }
      } else { v2 = val; i2 = m; }
    } else { v3 = val; i3 = m; }
  }
}

// k1: per pixel: channel max/min of x, channel mean of ref, copy x -> out[:, :3]
__global__ void k1_pixel(const float* __restrict__ x, const float* __restrict__ ref,
                         float* __restrict__ ws, float* __restrict__ out) {
  int id = blockIdx.x * 256 + threadIdx.x;
  if (id >= 2 * PSZ * PSZ) return;
  int b = id >> 16;
  int pix = id & 0xFFFF;
  const float* xb = x + (size_t)b * 3 * PSZ * PSZ + pix;
  float c0 = xb[0], c1 = xb[PSZ * PSZ], c2 = xb[2 * PSZ * PSZ];
  ws[OFF_CMAX + id] = fmaxf(fmaxf(c0, c1), c2);
  ws[OFF_CMIN + id] = fminf(fminf(c0, c1), c2);
  const float* rb = ref + (size_t)b * 3 * PSZ * PSZ + pix;
  ws[OFF_REFG + id] = (rb[0] + rb[PSZ * PSZ] + rb[2 * PSZ * PSZ]) / 3.0f;
  float* ob = out + (size_t)b * 7 * PSZ * PSZ + pix;
  ob[0] = c0; ob[PSZ * PSZ] = c1; ob[2 * PSZ * PSZ] = c2;
}

// k2: x_gray = 3x3 clipped-window max of cmax - cmin
__global__ void k2_gray(float* __restrict__ ws) {
  int id = blockIdx.x * 256 + threadIdx.x;
  if (id >= 2 * PSZ * PSZ) return;
  int b = id >> 16;
  int pix = id & 0xFFFF;
  int y = pix >> 8, xx = pix & 255;
  const float* cm = ws + OFF_CMAX + ((size_t)b << 16);
  float m = -3.402823466e+38f;
  for (int dy = -1; dy <= 1; ++dy) {
    int yy = y + dy;
    if (yy < 0 || yy > 255) continue;
    for (int dx = -1; dx <= 1; ++dx) {
      int xc = xx + dx;
      if (xc < 0 || xc > 255) continue;
      m = fmaxf(m, cm[yy * PSZ + xc]);
    }
  }
  ws[OFF_XG + id] = m - ws[OFF_CMIN + id];
}

// k3: per-patch norms (uncentered), values recomputed from gray images (L2-resident)
__global__ void k3_norms(float* __restrict__ ws) {
  int id = blockIdx.x * 256 + threadIdx.x;
  if (id >= 2 * L) return;
  int b = id / L, m = id % L;
  int i = m / NPATCH, j = m % NPATCH;
  const float* xg = ws + OFF_XG + ((size_t)b << 16);
  const float* rg = ws + OFF_REFG + ((size_t)b << 16);
  float si = 0.f, sr = 0.f;
  for (int di = 0; di < 3; ++di)
    for (int dj = 0; dj < 3; ++dj) {
      float vi = xg[(2 * i + di) * PSZ + 2 * j + dj];
      float vr = rg[(2 * i + di) * PSZ + 2 * j + dj];
      si += vi * vi;
      sr += vr * vr;
    }
  ws[OFF_NI + id] = sqrtf(si);
  ws[OFF_NR + id] = sqrtf(sr);
}

// k4: per-(b,p) mean over L in f64 (same value sequence/order as before)
__global__ void k4_mean(float* __restrict__ ws) {
  __shared__ double sm[256];
  int which = blockIdx.x / 18;  // 0 = input(xg), 1 = ref(rg)
  int bp = blockIdx.x % 18;
  int b = bp / 9, p = bp % 9;
  int di = p / 3, dj = p % 3;
  const float* g = ws + (which ? OFF_REFG : OFF_XG) + ((size_t)b << 16);
  double s = 0.0;
  for (int l = threadIdx.x; l < L; l += 256) {
    int i = l / NPATCH, j = l % NPATCH;
    s += (double)g[(2 * i + di) * PSZ + 2 * j + dj];
  }
  sm[threadIdx.x] = s;
  __syncthreads();
  for (int st = 128; st > 0; st >>= 1) {
    if ((int)threadIdx.x < st) sm[threadIdx.x] += sm[threadIdx.x + st];
    __syncthreads();
  }
  if (threadIdx.x == 0)
    ws[(which ? OFF_MUR : OFF_MUI) + bp] = (float)(sm[0] / (double)L);
}

// k5: A[b][l][9] = (ip - muI)/nI ; B[b][9][L] = (rp - muR)/nR  (values from gray imgs)
__global__ void k5_norm(float* __restrict__ ws) {
  int id = blockIdx.x * 256 + threadIdx.x;
  if (id >= 2 * L) return;
  int b = id / L, l = id % L;
  int i = l / NPATCH, j = l % NPATCH;
  const float* xg = ws + OFF_XG + ((size_t)b << 16);
  const float* rg = ws + OFF_REFG + ((size_t)b << 16);
  float ni = ws[OFF_NI + id], nr = ws[OFF_NR + id];
  for (int p = 0; p < 9; ++p) {
    int di = p / 3, dj = p % 3;
    float vi = xg[(2 * i + di) * PSZ + 2 * j + dj];
    float vr = rg[(2 * i + di) * PSZ + 2 * j + dj];
    float mi = ws[OFF_MUI + b * 9 + p];
    float mr = ws[OFF_MUR + b * 9 + p];
    ws[OFF_A + ((size_t)b * L + l) * 9 + p] = (vi - mi) / ni;
    ws[OFF_B + ((size_t)b * 9 + p) * L + l] = (vr - mr) / nr;
  }
}

// branchless insert of (v,m) into descending top-4; strict > keeps earlier-m on ties
#define INS1(v_, m_, T) {                                                        \
  bool c0 = (v_) > tv##T##0, c1 = (v_) > tv##T##1,                               \
       c2 = (v_) > tv##T##2, c3 = (v_) > tv##T##3;                               \
  tv##T##3 = c2 ? tv##T##2 : (c3 ? (v_) : tv##T##3);                             \
  ti##T##3 = c2 ? ti##T##2 : (c3 ? (m_) : ti##T##3);                             \
  tv##T##2 = c1 ? tv##T##1 : (c2 ? (v_) : tv##T##2);                             \
  ti##T##2 = c1 ? ti##T##1 : (c2 ? (m_) : ti##T##2);                             \
  tv##T##1 = c0 ? tv##T##0 : (c1 ? (v_) : tv##T##1);                             \
  ti##T##1 = c0 ? ti##T##0 : (c1 ? (m_) : ti##T##1);                             \
  tv##T##0 = c0 ? (v_) : tv##T##0;                                               \
  ti##T##0 = c0 ? (m_) : ti##T##0;                                               \
}

// k6: fused ncc + per-segment top-4.
// grid: 2(b) x 32(rowblk) x 16(seg) = 1024 blocks (4/CU), 256 threads,
// 2 rows/thread, 4 m/iter. __launch_bounds__(256,2) -> 64-VGPR budget
// (round-1-proven); per-thread state ~55 VGPR -> no scratch spill.
__global__ __launch_bounds__(TMAIN, 2) void k6_topk(float* __restrict__ ws) {
  __shared__ float lds[9 * MSTRIDE];  // 36432 B

  int bid = blockIdx.x;
  int seg = bid % NS;
  int rowblk = (bid / NS) % NROWBLK;
  int b = bid / (NS * NROWBLK);
  int m0 = seg * SEGLEN;
  int mend = m0 + SEGLEN;
  if (mend > L) mend = L;
  int mlen = mend - m0;

  const float* Bg = ws + OFF_B + (size_t)b * 9 * L + m0;
  for (int p = 0; p < 9; ++p)
    for (int mm = threadIdx.x; mm < mlen; mm += TMAIN)
      lds[p * MSTRIDE + mm] = Bg[(size_t)p * L + mm];
  __syncthreads();

  int row0 = rowblk * ROWS_PER_BLOCK + threadIdx.x * RPT;
  int r0 = row0 < L - 1 ? row0 : L - 1;
  int r1 = row0 + 1 < L - 1 ? row0 + 1 : L - 1;
  float a0[9], a1[9];
  {
    const float* Ap0 = ws + OFF_A + ((size_t)b * L + r0) * 9;
    const float* Ap1 = ws + OFF_A + ((size_t)b * L + r1) * 9;
#pragma unroll
    for (int p = 0; p < 9; ++p) { a0[p] = Ap0[p]; a1[p] = Ap1[p]; }
  }

  float tv00 = -3.402823466e+38f, tv01 = tv00, tv02 = tv00, tv03 = tv00;
  float tv10 = tv00, tv11 = tv00, tv12 = tv00, tv13 = tv00;
  int ti00 = 0, ti01 = 0, ti02 = 0, ti03 = 0;
  int ti10 = 0, ti11 = 0, ti12 = 0, ti13 = 0;

  int mlen4 = mlen & ~3;
  for (int mm = 0; mm < mlen4; mm += 4) {
    float s00, s01, s02, s03, s10, s11, s12, s13;
    {
      const float4 bq = *reinterpret_cast<const float4*>(&lds[mm]);
      s00 = a0[0] * bq.x; s01 = a0[0] * bq.y; s02 = a0[0] * bq.z; s03 = a0[0] * bq.w;
      s10 = a1[0] * bq.x; s11 = a1[0] * bq.y; s12 = a1[0] * bq.z; s13 = a1[0] * bq.w;
    }
#pragma unroll
    for (int p = 1; p < 9; ++p) {
      const float4 bq = *reinterpret_cast<const float4*>(&lds[p * MSTRIDE + mm]);
      s00 = fmaf(a0[p], bq.x, s00); s01 = fmaf(a0[p], bq.y, s01);
      s02 = fmaf(a0[p], bq.z, s02); s03 = fmaf(a0[p], bq.w, s03);
      s10 = fmaf(a1[p], bq.x, s10); s11 = fmaf(a1[p], bq.y, s11);
      s12 = fmaf(a1[p], bq.z, s12); s13 = fmaf(a1[p], bq.w, s13);
    }
    float rm0 = fmaxf(fmaxf(s00, s01), fmaxf(s02, s03));
    if (rm0 > tv03) {
      INS1(s00, m0 + mm + 0, 0); INS1(s01, m0 + mm + 1, 0);
      INS1(s02, m0 + mm + 2, 0); INS1(s03, m0 + mm + 3, 0);
    }
    float rm1 = fmaxf(fmaxf(s10, s11), fmaxf(s12, s13));
    if (rm1 > tv13) {
      INS1(s10, m0 + mm + 0, 1); INS1(s11, m0 + mm + 1, 1);
      INS1(s12, m0 + mm + 2, 1); INS1(s13, m0 + mm + 3, 1);
    }
  }
  for (int mm = mlen4; mm < mlen; ++mm) {
    float bb, sv0, sv1;
    bb = lds[mm]; sv0 = a0[0] * bb; sv1 = a1[0] * bb;
#pragma unroll
    for (int p = 1; p < 9; ++p) {
      bb = lds[p * MSTRIDE + mm];
      sv0 = fmaf(a0[p], bb, sv0); sv1 = fmaf(a1[p], bb, sv1);
    }
    if (sv0 > tv03) { INS1(sv0, m0 + mm, 0); }
    if (sv1 > tv13) { INS1(sv1, m0 + mm, 1); }
  }

  int* wsi = (int*)ws;
  if (row0 < L) {
    size_t base = (((size_t)b * NS + seg) * ROWPAD + row0) * 4;
    ws[OFF_PV + base + 0] = tv00; ws[OFF_PV + base + 1] = tv01;
    ws[OFF_PV + base + 2] = tv02; ws[OFF_PV + base + 3] = tv03;
    wsi[OFF_PI + base + 0] = ti00; wsi[OFF_PI + base + 1] = ti01;
    wsi[OFF_PI + base + 2] = ti02; wsi[OFF_PI + base + 3] = ti03;
  }
  if (row0 + 1 < L) {
    size_t base = (((size_t)b * NS + seg) * ROWPAD + row0 + 1) * 4;
    ws[OFF_PV + base + 0] = tv10; ws[OFF_PV + base + 1] = tv11;
    ws[OFF_PV + base + 2] = tv12; ws[OFF_PV + base + 3] = tv13;
    wsi[OFF_PI + base + 0] = ti10; wsi[OFF_PI + base + 1] = ti11;
    wsi[OFF_PI + base + 2] = ti12; wsi[OFF_PI + base + 3] = ti13;
  }
}

// k7: merge per-segment top-4 (segments ascending -> tie-break = lower m first)
__global__ void k7_merge(float* __restrict__ ws) {
  int id = blockIdx.x * 256 + threadIdx.x;
  if (id >= 2 * L) return;
  int b = id / L, row = id % L;
  float v0 = -3.402823466e+38f, v1 = v0, v2 = v0, v3 = v0;
  int i0 = 0, i1 = 0, i2 = 0, i3 = 0;
  const int* wsi_c = (const int*)ws;
  for (int s = 0; s < NS; ++s) {
    size_t base = (((size_t)b * NS + s) * ROWPAD + row) * 4;
    for (int q = 0; q < 4; ++q) {
      float val = ws[OFF_PV + base + q];
      int m = wsi_c[OFF_PI + base + q];
      ins4(val, m, v0, v1, v2, v3, i0, i1, i2, i3);
    }
  }
  int* wsi = (int*)ws;
  size_t ib = OFF_IDX + (size_t)id * 4;
  wsi[ib] = i0; wsi[ib + 1] = i1; wsi[ib + 2] = i2; wsi[ib + 3] = i3;
}

// k8: fold (overlap-add) via per-output-pixel gather; reads ref_gray directly
__global__ void k8_fold(const float* __restrict__ ws, float* __restrict__ out) {
  int id = blockIdx.x * 256 + threadIdx.x;
  if (id >= 2 * KTOP * PSZ * PSZ) return;
  int b = id / (KTOP * PSZ * PSZ);
  int rem = id % (KTOP * PSZ * PSZ);
  int kk = rem >> 16;
  int pix = rem & 0xFFFF;
  int y = pix >> 8, xx = pix & 255;
  const int* wsi = (const int*)ws;
  const float* rg = ws + OFF_REFG + ((size_t)b << 16);
  float acc = 0.f;
  for (int di = 0; di < 3; ++di) {
    int yy = y - di;
    if (yy < 0 || (yy & 1) || (yy >> 1) >= NPATCH) continue;
    int i = yy >> 1;
    for (int dj = 0; dj < 3; ++dj) {
      int xc = xx - dj;
      if (xc < 0 || (xc & 1) || (xc >> 1) >= NPATCH) continue;
      int j = xc >> 1;
      int l = i * NPATCH + j;
      int m = wsi[OFF_IDX + ((size_t)b * L + l) * 4 + kk];
      int mi = m / NPATCH, mj = m % NPATCH;
      acc += rg[(2 * mi + di) * PSZ + 2 * mj + dj];
    }
  }
  out[(((size_t)b * 7 + 3 + kk) * PSZ + y) * PSZ + xx] = acc;
}

extern "C" void kernel_launch(void* const* d_in, const int* in_sizes, int n_in,
                              void* d_out, int out_size, void* d_ws, size_t ws_size,
                              hipStream_t stream) {
  const float* x = (const float*)d_in[0];
  const float* ref = (const float*)d_in[1];
  float* ws = (float*)d_ws;
  float* out = (float*)d_out;

  k1_pixel<<<512, 256, 0, stream>>>(x, ref, ws, out);
  k2_gray<<<512, 256, 0, stream>>>(ws);
  k3_norms<<<(2 * L + 255) / 256, 256, 0, stream>>>(ws);
  k4_mean<<<36, 256, 0, stream>>>(ws);
  k5_norm<<<(2 * L + 255) / 256, 256, 0, stream>>>(ws);
  k6_topk<<<2 * NROWBLK * NS, TMAIN, 0, stream>>>(ws);
  k7_merge<<<(2 * L + 255) / 256, 256, 0, stream>>>(ws);
  k8_fold<<<(2 * KTOP * PSZ * PSZ + 255) / 256, 256, 0, stream>>>(ws, out);
}